// Round 2
// baseline (769.580 us; speedup 1.0000x reference)
//
#include <hip/hip_runtime.h>
#include <hip/hip_bf16.h>
#include <math.h>

#define S_LEN  2048
#define NBATCH 2
#define DMODEL 1024
#define NHEADS 16
#define HDIM   64
#define MROWS  (S_LEN*NBATCH)   // 4096

typedef __attribute__((ext_vector_type(8))) short          bf16x8;
typedef __attribute__((ext_vector_type(4))) float          f32x4;
typedef __attribute__((ext_vector_type(8))) unsigned short u16x8;

__device__ __forceinline__ unsigned short f2bf(float x) {
    union { __hip_bfloat16 h; unsigned short u; } c;
    c.h = __float2bfloat16(x);
    return c.u;
}

// ===================== fp32 -> bf16 convert (7 arrays in one launch) =====================
__global__ __launch_bounds__(256)
void cvt7(const float* __restrict__ s0, const float* __restrict__ s1,
          const float* __restrict__ s2, const float* __restrict__ s3,
          const float* __restrict__ s4, const float* __restrict__ s5,
          const float* __restrict__ s6,
          unsigned short* __restrict__ d0, unsigned short* __restrict__ d1,
          unsigned short* __restrict__ d2, unsigned short* __restrict__ d3,
          unsigned short* __restrict__ d4, unsigned short* __restrict__ d5,
          unsigned short* __restrict__ d6)
{
    const float* s; unsigned short* d; int n;
    switch (blockIdx.y) {
        case 0: s = s0; d = d0; n = MROWS*DMODEL;  break;
        case 1: s = s1; d = d1; n = MROWS*DMODEL;  break;
        case 2: s = s2; d = d2; n = MROWS*DMODEL;  break;
        case 3: s = s3; d = d3; n = DMODEL*DMODEL; break;
        case 4: s = s4; d = d4; n = DMODEL*DMODEL; break;
        case 5: s = s5; d = d5; n = DMODEL*DMODEL; break;
        default: s = s6; d = d6; n = DMODEL*DMODEL; break;
    }
    int i = (blockIdx.x*256 + threadIdx.x) * 8;
    if (i >= n) return;
    float4 a = *(const float4*)(s + i);
    float4 b = *(const float4*)(s + i + 4);
    u16x8 o;
    o[0] = f2bf(a.x); o[1] = f2bf(a.y); o[2] = f2bf(a.z); o[3] = f2bf(a.w);
    o[4] = f2bf(b.x); o[5] = f2bf(b.y); o[6] = f2bf(b.z); o[7] = f2bf(b.w);
    *(u16x8*)(d + i) = o;
}

// ===================== bf16 MFMA GEMM: C = A[M,K]bf16 @ W[N,K]bf16^T + bias =====================
// m97 structure: 128x128x32 tile, 256 thr = 4 waves (2x2), 16x16x32 MFMA, 4x4 frags/wave,
// linear LDS [128][32] bf16 staged via global_load_lds width=16.
// mode 0: C row-major [M, DMODEL].  mode 1: scatter to [B, H, S, HDIM].
#define GBM 128
#define GBN 128
#define GBK 32

__device__ __forceinline__ void gemm_bf16_core(
    const unsigned short* __restrict__ A,   // [M][1024] bf16
    const unsigned short* __restrict__ W,   // [N][1024] bf16 (K-contiguous)
    const float* __restrict__ bias,
    float* __restrict__ C, int mode)
{
    __shared__ __align__(16) unsigned short As[GBM*GBK];
    __shared__ __align__(16) unsigned short Bs[GBN*GBK];

    const int tid = threadIdx.x;
    const int l   = tid & 63;
    const int w   = tid >> 6;       // wave 0..3
    const int m0  = blockIdx.y * GBM;
    const int n0  = blockIdx.x * GBN;
    const int wm  = (w >> 1) * 64;  // wave row offset
    const int wn  = (w & 1) * 64;   // wave col offset

    f32x4 acc[4][4];
    #pragma unroll
    for (int i = 0; i < 4; ++i)
        #pragma unroll
        for (int j = 0; j < 4; ++j)
            acc[i][j] = (f32x4){0.f, 0.f, 0.f, 0.f};

    const int srow = l >> 2;        // 0..15: row within 16-row chunk
    const int scol = (l & 3) * 8;   // bf16 col offset (16B granules)

    for (int k0 = 0; k0 < DMODEL; k0 += GBK) {
        // stage A,B tiles: 8 KB each = 8 chunks of 1024B; wave w covers chunks w*2, w*2+1
        #pragma unroll
        for (int i = 0; i < 2; ++i) {
            int c = w*2 + i;
            const unsigned short* ga = A + (size_t)(m0 + c*16 + srow)*DMODEL + k0 + scol;
            const unsigned short* gb = W + (size_t)(n0 + c*16 + srow)*DMODEL + k0 + scol;
            __builtin_amdgcn_global_load_lds(
                (const __attribute__((address_space(1))) void*)ga,
                (__attribute__((address_space(3))) void*)(As + c*512), 16, 0, 0);
            __builtin_amdgcn_global_load_lds(
                (const __attribute__((address_space(1))) void*)gb,
                (__attribute__((address_space(3))) void*)(Bs + c*512), 16, 0, 0);
        }
        __syncthreads();   // drains vmcnt (compiler emits the waitcnt)

        bf16x8 af[4], bfr[4];
        #pragma unroll
        for (int f = 0; f < 4; ++f) {
            af[f]  = *(const bf16x8*)(As + (wm + f*16 + (l & 15))*GBK + (l >> 4)*8);
            bfr[f] = *(const bf16x8*)(Bs + (wn + f*16 + (l & 15))*GBK + (l >> 4)*8);
        }
        #pragma unroll
        for (int i = 0; i < 4; ++i)
            #pragma unroll
            for (int j = 0; j < 4; ++j)
                acc[i][j] = __builtin_amdgcn_mfma_f32_16x16x32_bf16(af[i], bfr[j], acc[i][j], 0, 0, 0);
        __syncthreads();
    }

    // epilogue: C/D layout col = l&15, row = (l>>4)*4 + reg  [m89/m91 verified]
    const int col_l = l & 15;
    const int row_l = (l >> 4) * 4;
    #pragma unroll
    for (int j = 0; j < 4; ++j) {
        int col = n0 + wn + j*16 + col_l;
        float bv = bias[col];
        #pragma unroll
        for (int i = 0; i < 4; ++i) {
            int mbase = m0 + wm + i*16 + row_l;
            #pragma unroll
            for (int r = 0; r < 4; ++r) {
                int m = mbase + r;
                float vout = acc[i][j][r] + bv;
                if (mode == 0) {
                    C[(size_t)m*DMODEL + col] = vout;
                } else {
                    int s = m >> 1, b = m & 1;       // A row = s*B + b
                    int h = col >> 6, d = col & 63;
                    C[((size_t)(b*NHEADS + h)*S_LEN + s)*HDIM + d] = vout;
                }
            }
        }
    }
}

__global__ __launch_bounds__(256)
void gemm_qkv_bf16(const unsigned short* __restrict__ qb, const unsigned short* __restrict__ kb,
                   const unsigned short* __restrict__ vb,
                   const unsigned short* __restrict__ Wqb, const float* __restrict__ bq,
                   const unsigned short* __restrict__ Wkb, const float* __restrict__ bk,
                   const unsigned short* __restrict__ Wvb, const float* __restrict__ bv,
                   float* __restrict__ qp, float* __restrict__ kp, float* __restrict__ vp)
{
    const int z = blockIdx.z;
    const unsigned short* A = (z==0) ? qb  : (z==1) ? kb  : vb;
    const unsigned short* W = (z==0) ? Wqb : (z==1) ? Wkb : Wvb;
    const float* bias       = (z==0) ? bq  : (z==1) ? bk  : bv;
    float* C                = (z==0) ? qp  : (z==1) ? kp  : vp;
    gemm_bf16_core(A, W, bias, C, 1);
}

__global__ __launch_bounds__(256)
void gemm_out_bf16(const unsigned short* __restrict__ A, const unsigned short* __restrict__ W,
                   const float* __restrict__ bias, float* __restrict__ C)
{
    gemm_bf16_core(A, W, bias, C, 0);
}

// ===================== Flash attention (fp32 vector), softmax over key axis =====================
// q/k/v fp32 in [B, H, S, HDIM]. Output bf16 [S, B, D].
#define QBLK  64
#define KVBLK 64

__global__ __launch_bounds__(256)
void attn_fwd(const float* __restrict__ qp, const float* __restrict__ kp,
              const float* __restrict__ vp, unsigned short* __restrict__ x)
{
    __shared__ float Qs[QBLK][HDIM+4];    // stride 68
    __shared__ float Ks[KVBLK][HDIM+4];   // K tile, reused as P tile after QK^T
    __shared__ float Vs[KVBLK][HDIM+4];

    const int tid = threadIdx.x;
    const int q0  = blockIdx.x * QBLK;
    const int bh  = blockIdx.y;            // b*NHEADS + h
    const int b   = bh >> 4;
    const int h   = bh & 15;
    const size_t base = (size_t)bh * S_LEN * HDIM;

    const int ra = tid >> 4;   // 0..15
    const int kb = tid & 15;   // 0..15

    #pragma unroll
    for (int it = 0; it < 4; ++it) {
        int f = tid + it*256;
        int row = f >> 4, c4 = f & 15;
        *(float4*)&Qs[row][c4*4] =
            *(const float4*)(qp + base + (size_t)(q0+row)*HDIM + c4*4);
    }

    float run_m[4], run_l[4];
    float4 o4[4];
    #pragma unroll
    for (int u = 0; u < 4; ++u) {
        run_m[u] = -1e30f; run_l[u] = 0.f;
        o4[u] = make_float4(0.f, 0.f, 0.f, 0.f);
    }

    for (int kt = 0; kt < S_LEN; kt += KVBLK) {
        #pragma unroll
        for (int it = 0; it < 4; ++it) {
            int f = tid + it*256;
            int row = f >> 4, c4 = f & 15;
            *(float4*)&Ks[row][c4*4] =
                *(const float4*)(kp + base + (size_t)(kt+row)*HDIM + c4*4);
            *(float4*)&Vs[row][c4*4] =
                *(const float4*)(vp + base + (size_t)(kt+row)*HDIM + c4*4);
        }
        __syncthreads();

        // ---- Phase A: QK^T, 4 rows x 4 kj per thread ----
        float s[4][4];
        #pragma unroll
        for (int ur = 0; ur < 4; ++ur)
            #pragma unroll
            for (int uk = 0; uk < 4; ++uk) s[ur][uk] = 0.f;

        #pragma unroll
        for (int d0 = 0; d0 < 16; ++d0) {
            float4 k4[4];
            #pragma unroll
            for (int uk = 0; uk < 4; ++uk)
                k4[uk] = *(const float4*)&Ks[kb + 16*uk][d0*4];
            #pragma unroll
            for (int ur = 0; ur < 4; ++ur) {
                float4 q4 = *(const float4*)&Qs[ra + 16*ur][d0*4];
                #pragma unroll
                for (int uk = 0; uk < 4; ++uk)
                    s[ur][uk] += q4.x*k4[uk].x + q4.y*k4[uk].y
                               + q4.z*k4[uk].z + q4.w*k4[uk].w;
            }
        }

        // ---- online softmax over key axis (16-lane groups share a row) ----
        float p[4][4];
        #pragma unroll
        for (int ur = 0; ur < 4; ++ur) {
            float mt = -1e30f;
            #pragma unroll
            for (int uk = 0; uk < 4; ++uk) { s[ur][uk] *= 0.125f; mt = fmaxf(mt, s[ur][uk]); }
            #pragma unroll
            for (int off = 1; off < 16; off <<= 1) mt = fmaxf(mt, __shfl_xor(mt, off));
            float mn = fmaxf(run_m[ur], mt);
            float al = __expf(run_m[ur] - mn);
            float ps = 0.f;
            #pragma unroll
            for (int uk = 0; uk < 4; ++uk) { p[ur][uk] = __expf(s[ur][uk] - mn); ps += p[ur][uk]; }
            #pragma unroll
            for (int off = 1; off < 16; off <<= 1) ps += __shfl_xor(ps, off);
            run_l[ur] = run_l[ur]*al + ps;
            run_m[ur] = mn;
            o4[ur].x *= al; o4[ur].y *= al; o4[ur].z *= al; o4[ur].w *= al;
        }

        __syncthreads();   // K tile dead -> reuse as P
        #pragma unroll
        for (int ur = 0; ur < 4; ++ur)
            #pragma unroll
            for (int uk = 0; uk < 4; ++uk)
                Ks[ra + 16*ur][kb + 16*uk] = p[ur][uk];
        __syncthreads();

        // ---- Phase B: O += P @ V ----
        #pragma unroll 4
        for (int kj0 = 0; kj0 < 16; ++kj0) {
            float4 v4[4];
            #pragma unroll
            for (int uv = 0; uv < 4; ++uv)
                v4[uv] = *(const float4*)&Vs[kj0*4 + uv][kb*4];
            #pragma unroll
            for (int ur = 0; ur < 4; ++ur) {
                float4 p4 = *(const float4*)&Ks[ra + 16*ur][kj0*4];
                o4[ur].x += p4.x*v4[0].x + p4.y*v4[1].x + p4.z*v4[2].x + p4.w*v4[3].x;
                o4[ur].y += p4.x*v4[0].y + p4.y*v4[1].y + p4.z*v4[2].y + p4.w*v4[3].y;
                o4[ur].z += p4.x*v4[0].z + p4.y*v4[1].z + p4.z*v4[2].z + p4.w*v4[3].z;
                o4[ur].w += p4.x*v4[0].w + p4.y*v4[1].w + p4.z*v4[2].w + p4.w*v4[3].w;
            }
        }
        __syncthreads();
    }

    // ---- finalize: normalize, emit bf16 directly (feeds out-GEMM) ----
    #pragma unroll
    for (int ur = 0; ur < 4; ++ur) {
        int r = ra + 16*ur;
        float inv = 1.f / run_l[ur];
        ushort4 ov;
        ov.x = f2bf(o4[ur].x * inv);
        ov.y = f2bf(o4[ur].y * inv);
        ov.z = f2bf(o4[ur].z * inv);
        ov.w = f2bf(o4[ur].w * inv);
        *(ushort4*)(x + ((size_t)((q0+r)*NBATCH + b))*DMODEL + h*HDIM + kb*4) = ov;
    }
}

// ===================== launch =====================
extern "C" void kernel_launch(void* const* d_in, const int* in_sizes, int n_in,
                              void* d_out, int out_size, void* d_ws, size_t ws_size,
                              hipStream_t stream)
{
    const float* query = (const float*)d_in[0];
    const float* key_i = (const float*)d_in[1];
    const float* value = (const float*)d_in[2];
    const float* Wq = (const float*)d_in[3];
    const float* bq = (const float*)d_in[4];
    const float* Wk = (const float*)d_in[5];
    const float* bk = (const float*)d_in[6];
    const float* Wv = (const float*)d_in[7];
    const float* bv = (const float*)d_in[8];
    const float* Wo = (const float*)d_in[9];
    const float* bo = (const float*)d_in[10];
    float* out = (float*)d_out;

    // workspace layout (bytes):
    //   0    qb  bf16 4096x1024   (8 MB)
    //   8M   kb                   (8 MB)
    //   16M  vb                   (8 MB)
    //   24M  Wqb bf16 1024x1024   (2 MB)
    //   26M  Wkb                  (2 MB)
    //   28M  Wvb                  (2 MB)
    //   30M  Wob                  (2 MB)
    //   32M  qp  f32 [B,H,S,64]   (16 MB)
    //   48M  kp                   (16 MB)
    //   64M  vp                   (16 MB)
    //   80M  xab bf16 [S,B,D]     (8 MB)   total 88 MB
    char* ws = (char*)d_ws;
    unsigned short* qb  = (unsigned short*)(ws);
    unsigned short* kb2 = (unsigned short*)(ws + (size_t) 8*1024*1024);
    unsigned short* vb  = (unsigned short*)(ws + (size_t)16*1024*1024);
    unsigned short* Wqb = (unsigned short*)(ws + (size_t)24*1024*1024);
    unsigned short* Wkb = (unsigned short*)(ws + (size_t)26*1024*1024);
    unsigned short* Wvb = (unsigned short*)(ws + (size_t)28*1024*1024);
    unsigned short* Wob = (unsigned short*)(ws + (size_t)30*1024*1024);
    float*          qp  = (float*)         (ws + (size_t)32*1024*1024);
    float*          kp  = (float*)         (ws + (size_t)48*1024*1024);
    float*          vp  = (float*)         (ws + (size_t)64*1024*1024);
    unsigned short* xab = (unsigned short*)(ws + (size_t)80*1024*1024);

    // 1) convert the 7 read-side arrays to bf16
    dim3 gCvt(MROWS*DMODEL/(256*8), 7);          // (2048, 7)
    cvt7<<<gCvt, 256, 0, stream>>>(query, key_i, value, Wq, Wk, Wv, Wo,
                                   qb, kb2, vb, Wqb, Wkb, Wvb, Wob);

    // 2) fused QKV projections (bf16 MFMA), scatter to [B,H,S,64] fp32
    dim3 gProj(DMODEL/GBN, MROWS/GBM, 3);        // (8, 32, 3)
    gemm_qkv_bf16<<<gProj, 256, 0, stream>>>(qb, kb2, vb,
                                             Wqb, bq, Wkb, bk, Wvb, bv,
                                             qp, kp, vp);

    // 3) flash attention (fp32), emits bf16 [S,B,D]
    dim3 gAttn(S_LEN/QBLK, NBATCH*NHEADS);       // (32, 32)
    attn_fwd<<<gAttn, 256, 0, stream>>>(qp, kp, vp, xab);

    // 4) output projection (bf16 MFMA), fp32 out
    dim3 gOut(DMODEL/GBN, MROWS/GBM, 1);         // (8, 32)
    gemm_out_bf16<<<gOut, 256, 0, stream>>>(xab, Wob, bo, out);
}

// Round 4
// 259.647 us; speedup vs baseline: 2.9640x; 2.9640x over previous
//
#include <hip/hip_runtime.h>
#include <hip/hip_bf16.h>
#include <math.h>

#define S_LEN  2048
#define NBATCH 2
#define DMODEL 1024
#define NHEADS 16
#define HDIM   64
#define MROWS  (S_LEN*NBATCH)   // 4096
#define NBH    (NBATCH*NHEADS)  // 32

typedef __attribute__((ext_vector_type(8))) short          bf16x8;
typedef __attribute__((ext_vector_type(4))) float          f32x4;
typedef __attribute__((ext_vector_type(8))) unsigned short u16x8;

__device__ __forceinline__ unsigned short f2bf(float x) {
    union { __hip_bfloat16 h; unsigned short u; } c;
    c.h = __float2bfloat16(x);
    return c.u;
}
__device__ __forceinline__ unsigned int pk2(float a, float b) {
    return (unsigned int)f2bf(a) | ((unsigned int)f2bf(b) << 16);
}

// ===================== fp32 -> bf16 convert (7 arrays in one launch) =====================
__global__ __launch_bounds__(256)
void cvt7(const float* __restrict__ s0, const float* __restrict__ s1,
          const float* __restrict__ s2, const float* __restrict__ s3,
          const float* __restrict__ s4, const float* __restrict__ s5,
          const float* __restrict__ s6,
          unsigned short* __restrict__ d0, unsigned short* __restrict__ d1,
          unsigned short* __restrict__ d2, unsigned short* __restrict__ d3,
          unsigned short* __restrict__ d4, unsigned short* __restrict__ d5,
          unsigned short* __restrict__ d6)
{
    const float* s; unsigned short* d; int n;
    switch (blockIdx.y) {
        case 0: s = s0; d = d0; n = MROWS*DMODEL;  break;
        case 1: s = s1; d = d1; n = MROWS*DMODEL;  break;
        case 2: s = s2; d = d2; n = MROWS*DMODEL;  break;
        case 3: s = s3; d = d3; n = DMODEL*DMODEL; break;
        case 4: s = s4; d = d4; n = DMODEL*DMODEL; break;
        case 5: s = s5; d = d5; n = DMODEL*DMODEL; break;
        default: s = s6; d = d6; n = DMODEL*DMODEL; break;
    }
    int i = (blockIdx.x*256 + threadIdx.x) * 8;
    if (i >= n) return;
    float4 a = *(const float4*)(s + i);
    float4 b = *(const float4*)(s + i + 4);
    u16x8 o;
    o[0] = f2bf(a.x); o[1] = f2bf(a.y); o[2] = f2bf(a.z); o[3] = f2bf(a.w);
    o[4] = f2bf(b.x); o[5] = f2bf(b.y); o[6] = f2bf(b.z); o[7] = f2bf(b.w);
    *(u16x8*)(d + i) = o;
}

// ===================== bf16 MFMA GEMM: C = A[M,K]bf16 @ W[N,K]bf16^T + bias =====================
// mode 0: fp32 C row-major [M, DMODEL]
// mode 1: bf16 scatter to [B,H,S,HDIM], value scaled by `scale` (Q gets 0.125)
// mode 2: bf16 scatter TRANSPOSED to [B,H,HDIM,S]  (V^T for attention PV B-operand)
#define GBM 128
#define GBN 128
#define GBK 32

__device__ __forceinline__ void gemm_bf16_core(
    const unsigned short* __restrict__ A,
    const unsigned short* __restrict__ W,
    const float* __restrict__ bias,
    float* __restrict__ Cf, unsigned short* __restrict__ Cb,
    int mode, float scale)
{
    __shared__ __align__(16) unsigned short As[GBM*GBK];
    __shared__ __align__(16) unsigned short Bs[GBN*GBK];

    const int tid = threadIdx.x;
    const int l   = tid & 63;
    const int w   = tid >> 6;
    const int m0  = blockIdx.y * GBM;
    const int n0  = blockIdx.x * GBN;
    const int wm  = (w >> 1) * 64;
    const int wn  = (w & 1) * 64;

    f32x4 acc[4][4];
    #pragma unroll
    for (int i = 0; i < 4; ++i)
        #pragma unroll
        for (int j = 0; j < 4; ++j)
            acc[i][j] = (f32x4){0.f, 0.f, 0.f, 0.f};

    const int srow = l >> 2;
    const int scol = (l & 3) * 8;

    for (int k0 = 0; k0 < DMODEL; k0 += GBK) {
        #pragma unroll
        for (int i = 0; i < 2; ++i) {
            int c = w*2 + i;
            const unsigned short* ga = A + (size_t)(m0 + c*16 + srow)*DMODEL + k0 + scol;
            const unsigned short* gb = W + (size_t)(n0 + c*16 + srow)*DMODEL + k0 + scol;
            __builtin_amdgcn_global_load_lds(
                (const __attribute__((address_space(1))) void*)ga,
                (__attribute__((address_space(3))) void*)(As + c*512), 16, 0, 0);
            __builtin_amdgcn_global_load_lds(
                (const __attribute__((address_space(1))) void*)gb,
                (__attribute__((address_space(3))) void*)(Bs + c*512), 16, 0, 0);
        }
        __syncthreads();

        bf16x8 af[4], bfr[4];
        #pragma unroll
        for (int f = 0; f < 4; ++f) {
            af[f]  = *(const bf16x8*)(As + (wm + f*16 + (l & 15))*GBK + (l >> 4)*8);
            bfr[f] = *(const bf16x8*)(Bs + (wn + f*16 + (l & 15))*GBK + (l >> 4)*8);
        }
        #pragma unroll
        for (int i = 0; i < 4; ++i)
            #pragma unroll
            for (int j = 0; j < 4; ++j)
                acc[i][j] = __builtin_amdgcn_mfma_f32_16x16x32_bf16(af[i], bfr[j], acc[i][j], 0, 0, 0);
        __syncthreads();
    }

    const int col_l = l & 15;
    const int row_l = (l >> 4) * 4;
    #pragma unroll
    for (int j = 0; j < 4; ++j) {
        int col = n0 + wn + j*16 + col_l;
        float bv = bias[col];
        #pragma unroll
        for (int i = 0; i < 4; ++i) {
            int mbase = m0 + wm + i*16 + row_l;
            #pragma unroll
            for (int r = 0; r < 4; ++r) {
                int m = mbase + r;
                float vout = (acc[i][j][r] + bv) * scale;
                if (mode == 0) {
                    Cf[(size_t)m*DMODEL + col] = vout;
                } else {
                    int s = m >> 1, b = m & 1;       // A row = s*NBATCH + b
                    int h = col >> 6, d = col & 63;
                    if (mode == 1)
                        Cb[((size_t)(b*NHEADS + h)*S_LEN + s)*HDIM + d] = f2bf(vout);
                    else
                        Cb[((size_t)(b*NHEADS + h)*HDIM + d)*S_LEN + s] = f2bf(vout);
                }
            }
        }
    }
}

__global__ __launch_bounds__(256)
void gemm_qkv_bf16(const unsigned short* __restrict__ qb, const unsigned short* __restrict__ kb,
                   const unsigned short* __restrict__ vb,
                   const unsigned short* __restrict__ Wqb, const float* __restrict__ bq,
                   const unsigned short* __restrict__ Wkb, const float* __restrict__ bk,
                   const unsigned short* __restrict__ Wvb, const float* __restrict__ bv,
                   unsigned short* __restrict__ qp, unsigned short* __restrict__ kp,
                   unsigned short* __restrict__ vt)
{
    const int z = blockIdx.z;
    const unsigned short* A = (z==0) ? qb  : (z==1) ? kb  : vb;
    const unsigned short* W = (z==0) ? Wqb : (z==1) ? Wkb : Wvb;
    const float* bias       = (z==0) ? bq  : (z==1) ? bk  : bv;
    unsigned short* C       = (z==0) ? qp  : (z==1) ? kp  : vt;
    int   mode  = (z==2) ? 2 : 1;
    float scale = (z==0) ? 0.125f : 1.0f;   // fold 1/sqrt(dk) into Q (exact in bf16)
    gemm_bf16_core(A, W, bias, nullptr, C, mode, scale);
}

__global__ __launch_bounds__(256)
void gemm_out_bf16(const unsigned short* __restrict__ A, const unsigned short* __restrict__ W,
                   const float* __restrict__ bias, float* __restrict__ C)
{
    gemm_bf16_core(A, W, bias, C, nullptr, 0, 1.0f);
}

// ===================== Flash attention, bf16 MFMA, swapped QK^T =====================
// qp,kp: [BH][S][64] bf16 (Q pre-scaled by 0.125). vt: [BH][64][S] bf16. x: [S*B][1024] bf16.
// Block: 256 thr = 4 waves; QBLK=128 (32 q-rows/wave); KVBLK=64.
// S^T = mfma(K,Q): lane holds S^T[key = mi*16+4g+reg][row = ni*16+s16] -> softmax mostly in-lane.
// P -> per-wave swizzled LDS (ds_write_b64) -> A-frag reads for PV. K/Vt staged with
// pre-swizzled global source so all frag reads are <=2-way bank aliased.
#define QBLK  128
#define KVBLK 64

__global__ __launch_bounds__(256)
void attn_mfma(const unsigned short* __restrict__ qp, const unsigned short* __restrict__ kp,
               const unsigned short* __restrict__ vt, unsigned short* __restrict__ x)
{
    __shared__ __align__(16) unsigned short Ks[KVBLK*HDIM];     // 8 KB, swizzled rows=key
    __shared__ __align__(16) unsigned short Vs[HDIM*KVBLK];     // 8 KB, swizzled rows=d
    __shared__ __align__(16) unsigned short Ps[4][32*KVBLK];    // 4x4 KB per-wave P

    const int tid = threadIdx.x;
    const int w   = tid >> 6;
    const int l   = tid & 63;
    const int g   = l >> 4;
    const int s16 = l & 15;
    const int q0  = blockIdx.x * QBLK;
    const int bh  = blockIdx.y;
    const int b   = bh >> 4;
    const int h   = bh & 15;
    const size_t base = (size_t)bh * S_LEN * HDIM;   // same element count for vt

    char* KsB = (char*)Ks;
    char* VsB = (char*)Vs;
    char* PsB = (char*)&Ps[w][0];

    // Q fragments (B-operand): row = q0 + w*32 + ni*16 + s16, d = ks*32 + g*8
    bf16x8 qf[2][2];
    #pragma unroll
    for (int ni = 0; ni < 2; ++ni)
        #pragma unroll
        for (int ks = 0; ks < 2; ++ks) {
            int qrow = q0 + w*32 + ni*16 + s16;
            qf[ni][ks] = *(const bf16x8*)(qp + base + (size_t)qrow*HDIM + ks*32 + g*8);
        }

    f32x4 oacc[2][4];
    #pragma unroll
    for (int ni = 0; ni < 2; ++ni)
        #pragma unroll
        for (int nj = 0; nj < 4; ++nj)
            oacc[ni][nj] = (f32x4){0.f, 0.f, 0.f, 0.f};
    float run_m[2] = {-1e30f, -1e30f};
    float run_l[2] = {0.f, 0.f};

    for (int kt = 0; kt < S_LEN; kt += KVBLK) {
        // ---- stage K and Vt tiles (8 KB each) with pre-swizzled source ----
        // LDS linear chunk idx: row = idx>>3, slot = idx&7; source slot = slot ^ (row&7)
        #pragma unroll
        for (int it = 0; it < 2; ++it) {
            int idx  = it*256 + tid;
            int row  = idx >> 3;
            int u    = (idx & 7) ^ (row & 7);
            const unsigned short* gk = kp + base + (size_t)(kt + row)*HDIM + u*8;
            __builtin_amdgcn_global_load_lds(
                (const __attribute__((address_space(1))) void*)gk,
                (__attribute__((address_space(3))) void*)(Ks + (it*256 + w*64)*8), 16, 0, 0);
            const unsigned short* gv = vt + base + (size_t)row*S_LEN + kt + u*8;
            __builtin_amdgcn_global_load_lds(
                (const __attribute__((address_space(1))) void*)gv,
                (__attribute__((address_space(3))) void*)(Vs + (it*256 + w*64)*8), 16, 0, 0);
        }
        __syncthreads();

        // ---- QK^T (swapped): S^T[key][row] = sum_d K[key][d] * Q[row][d] ----
        f32x4 sacc[4][2];
        #pragma unroll
        for (int mi = 0; mi < 4; ++mi)
            #pragma unroll
            for (int ni = 0; ni < 2; ++ni)
                sacc[mi][ni] = (f32x4){0.f, 0.f, 0.f, 0.f};

        #pragma unroll
        for (int ks = 0; ks < 2; ++ks) {
            bf16x8 af[4];
            #pragma unroll
            for (int mi = 0; mi < 4; ++mi) {
                int key  = mi*16 + s16;
                int addr = ((key << 7) + (ks << 6) + (g << 4)) ^ ((key & 7) << 4);
                af[mi] = *(const bf16x8*)(KsB + addr);
            }
            #pragma unroll
            for (int mi = 0; mi < 4; ++mi)
                #pragma unroll
                for (int ni = 0; ni < 2; ++ni)
                    sacc[mi][ni] = __builtin_amdgcn_mfma_f32_16x16x32_bf16(
                        af[mi], qf[ni][ks], sacc[mi][ni], 0, 0, 0);
        }

        // ---- online softmax (lane owns 16 of 64 keys for row ni*16+s16) ----
        float al[2];
        #pragma unroll
        for (int ni = 0; ni < 2; ++ni) {
            float tm = -1e30f;
            #pragma unroll
            for (int mi = 0; mi < 4; ++mi)
                #pragma unroll
                for (int r = 0; r < 4; ++r)
                    tm = fmaxf(tm, sacc[mi][ni][r]);
            tm = fmaxf(tm, __shfl_xor(tm, 16));
            tm = fmaxf(tm, __shfl_xor(tm, 32));
            float mn = fmaxf(run_m[ni], tm);
            al[ni] = __expf(run_m[ni] - mn);
            float ps = 0.f;
            int row = ni*16 + s16;
            #pragma unroll
            for (int mi = 0; mi < 4; ++mi) {
                float p0 = __expf(sacc[mi][ni][0] - mn);
                float p1 = __expf(sacc[mi][ni][1] - mn);
                float p2 = __expf(sacc[mi][ni][2] - mn);
                float p3 = __expf(sacc[mi][ni][3] - mn);
                ps += (p0 + p1) + (p2 + p3);
                // P[row][key], key = mi*16 + g*4 + reg; b64 packed write, swizzled
                uint2 wv; wv.x = pk2(p0, p1); wv.y = pk2(p2, p3);
                int addr = ((row << 7) + (mi << 5) + (g << 3)) ^ ((row & 7) << 4);
                *(uint2*)(PsB + addr) = wv;
            }
            ps += __shfl_xor(ps, 16);
            ps += __shfl_xor(ps, 32);
            run_l[ni] = run_l[ni]*al[ni] + ps;
            run_m[ni] = mn;
        }

        // ---- rescale O: alpha for O-row (4g+r) fetched from lane holding that row ----
        float alo[2][4];
        #pragma unroll
        for (int ni = 0; ni < 2; ++ni)
            #pragma unroll
            for (int r = 0; r < 4; ++r)
                alo[ni][r] = __shfl(al[ni], 20*g + r);   // lane 16g + (4g+r)
        #pragma unroll
        for (int ni = 0; ni < 2; ++ni)
            #pragma unroll
            for (int nj = 0; nj < 4; ++nj)
                #pragma unroll
                for (int r = 0; r < 4; ++r)
                    oacc[ni][nj][r] *= alo[ni][r];

        // ---- PV: O[row][d] += P[row][key] @ Vt[d][key] ----
        #pragma unroll
        for (int ks = 0; ks < 2; ++ks) {
            bf16x8 pa[2];
            #pragma unroll
            for (int ni = 0; ni < 2; ++ni) {
                int row  = ni*16 + s16;
                int addr = ((row << 7) + (ks << 6) + (g << 4)) ^ ((row & 7) << 4);
                pa[ni] = *(const bf16x8*)(PsB + addr);
            }
            bf16x8 bv[4];
            #pragma unroll
            for (int nj = 0; nj < 4; ++nj) {
                int d    = nj*16 + s16;
                int addr = ((d << 7) + (ks << 6) + (g << 4)) ^ ((d & 7) << 4);
                bv[nj] = *(const bf16x8*)(VsB + addr);
            }
            #pragma unroll
            for (int ni = 0; ni < 2; ++ni)
                #pragma unroll
                for (int nj = 0; nj < 4; ++nj)
                    oacc[ni][nj] = __builtin_amdgcn_mfma_f32_16x16x32_bf16(
                        pa[ni], bv[nj], oacc[ni][nj], 0, 0, 0);
        }
        __syncthreads();   // before next tile overwrites Ks/Vs
    }

    // ---- finalize: O-row r' = ni*16+4g+r, divide by run_l[r'], emit bf16 [S*B][1024] ----
    #pragma unroll
    for (int ni = 0; ni < 2; ++ni) {
        #pragma unroll
        for (int r = 0; r < 4; ++r) {
            float rl  = __shfl(run_l[ni], 20*g + r);
            float inv = 1.f / rl;
            int row = q0 + w*32 + ni*16 + 4*g + r;
            #pragma unroll
            for (int nj = 0; nj < 4; ++nj) {
                int col = h*HDIM + nj*16 + s16;
                x[(size_t)(row*NBATCH + b)*DMODEL + col] = f2bf(oacc[ni][nj][r] * inv);
            }
        }
    }
}

// ===================== launch =====================
extern "C" void kernel_launch(void* const* d_in, const int* in_sizes, int n_in,
                              void* d_out, int out_size, void* d_ws, size_t ws_size,
                              hipStream_t stream)
{
    const float* query = (const float*)d_in[0];
    const float* key_i = (const float*)d_in[1];
    const float* value = (const float*)d_in[2];
    const float* Wq = (const float*)d_in[3];
    const float* bq = (const float*)d_in[4];
    const float* Wk = (const float*)d_in[5];
    const float* bk = (const float*)d_in[6];
    const float* Wv = (const float*)d_in[7];
    const float* bv = (const float*)d_in[8];
    const float* Wo = (const float*)d_in[9];
    const float* bo = (const float*)d_in[10];
    float* out = (float*)d_out;

    // workspace (MB offsets): qb 0, kb 8, vb 16, Wqb 24, Wkb 26, Wvb 28, Wob 30,
    // qp 32, kp 40, vt 48, xab 56  -> 64 MB total
    char* ws = (char*)d_ws;
    unsigned short* qb  = (unsigned short*)(ws);
    unsigned short* kb2 = (unsigned short*)(ws + (size_t) 8*1024*1024);
    unsigned short* vb  = (unsigned short*)(ws + (size_t)16*1024*1024);
    unsigned short* Wqb = (unsigned short*)(ws + (size_t)24*1024*1024);
    unsigned short* Wkb = (unsigned short*)(ws + (size_t)26*1024*1024);
    unsigned short* Wvb = (unsigned short*)(ws + (size_t)28*1024*1024);
    unsigned short* Wob = (unsigned short*)(ws + (size_t)30*1024*1024);
    unsigned short* qp  = (unsigned short*)(ws + (size_t)32*1024*1024);
    unsigned short* kp  = (unsigned short*)(ws + (size_t)40*1024*1024);
    unsigned short* vt  = (unsigned short*)(ws + (size_t)48*1024*1024);
    unsigned short* xab = (unsigned short*)(ws + (size_t)56*1024*1024);

    dim3 gCvt(MROWS*DMODEL/(256*8), 7);
    cvt7<<<gCvt, 256, 0, stream>>>(query, key_i, value, Wq, Wk, Wv, Wo,
                                   qb, kb2, vb, Wqb, Wkb, Wvb, Wob);

    dim3 gProj(DMODEL/GBN, MROWS/GBM, 3);
    gemm_qkv_bf16<<<gProj, 256, 0, stream>>>(qb, kb2, vb,
                                             Wqb, bq, Wkb, bk, Wvb, bv,
                                             qp, kp, vt);

    dim3 gAttn(S_LEN/QBLK, NBH);           // (16, 32)
    attn_mfma<<<gAttn, 256, 0, stream>>>(qp, kp, vt, xab);

    dim3 gOut(DMODEL/GBN, MROWS/GBM, 1);
    gemm_out_bf16<<<gOut, 256, 0, stream>>>(xab, Wob, bo, out);
}